// Round 4
// baseline (49.074 us; speedup 1.0000x reference)
//
#include <hip/hip_runtime.h>
#include <math.h>

#define MARGIN 0.2f
#define NEG_WEIGHT 0.5f

constexpr int Bc = 64, Nc = 16, Lc = 1024, DH = 64, Ac = 8;
constexpr int NSAMP = Bc * Ac;         // 512
constexpr int CHUNKS = 16;
constexpr int RPC = Lc / CHUNKS;       // 64 rows per chunk

__device__ __forceinline__ float pdist(float x2, float y2, float d2) {
    x2 = fminf(x2, 0.999999f);
    y2 = fminf(y2, 0.999999f);
    float num = 2.0f * d2;
    float den = (1.0f - x2) * (1.0f - y2);
    float ratio = num * __builtin_amdgcn_rcpf(fmaxf(den, 1e-15f));
    float z = 1.0f + fmaxf(ratio, 1.0f + 1e-7f);
    // z >= 1 + 1e-7: acosh via log
    return __logf(z + __builtin_sqrtf(z * z - 1.0f));
}

// block = (s, c). Reads ONLY rows in [max(c*64, lt+1), c*64+64) — rows <= lt
// are masked to zero by the reference and need never be read.
// lane layout: quad = lane&3 owns 16 dims; rg = lane>>2 owns a row.
__global__ __launch_bounds__(64) void sample_kernel(
    const float* __restrict__ h_curr,
    const float* __restrict__ demo_h,
    const int*   __restrict__ align_idx,
    const int*   __restrict__ lookahead_p,
    float* __restrict__ wneg,   // [CHUNKS][NSAMP] hinge partial sums
    float* __restrict__ wpos)   // [NSAMP] d_pos (0 if invalid)
{
    const int blk  = blockIdx.x;
    const int s    = blk >> 4;
    const int c    = blk & 15;
    const int b    = s >> 3;
    const int lane = threadIdx.x;
    const int quad = lane & 3;
    const int rg   = lane >> 2;

    const int l0 = align_idx[s * 2 + 1];
    const int lt = l0 + lookahead_p[0];
    const bool valid = (lt >= 0) && (lt < Lc);

    if (!valid) {
        if (lane == 0) {
            wneg[c * NSAMP + s] = 0.0f;
            if (c == 0) wpos[s] = 0.0f;
        }
        return;
    }

    const int rowlo = max(c * RPC, lt + 1);
    const int rowhi = c * RPC + RPC;
    const bool empty = rowlo >= rowhi;

    // empty chunks contribute 0 hinge; only c==0 must stay alive (for d_pos)
    if (empty && c != 0) {
        if (lane == 0) wneg[c * NSAMP + s] = 0.0f;
        return;
    }

    const int n0 = align_idx[s * 2 + 0];
    const float* __restrict__ xrow = h_curr + (size_t)b * DH + quad * 16;
    const float* __restrict__ seq  = demo_h + (((size_t)b * Nc + (size_t)n0) * Lc) * DH;

    float4 xv[4];
    #pragma unroll
    for (int j = 0; j < 4; ++j)
        xv[j] = *reinterpret_cast<const float4*>(xrow + j * 4);

    float x2 = 0.0f;
    #pragma unroll
    for (int j = 0; j < 4; ++j) {
        x2 = fmaf(xv[j].x, xv[j].x, x2); x2 = fmaf(xv[j].y, xv[j].y, x2);
        x2 = fmaf(xv[j].z, xv[j].z, x2); x2 = fmaf(xv[j].w, xv[j].w, x2);
    }
    x2 += __shfl_xor(x2, 1, 64);
    x2 += __shfl_xor(x2, 2, 64);

    // d_pos from row lt (valid => lt in [0, L-1], clamp is identity)
    float d_pos;
    {
        const int ltc = min(max(lt, 0), Lc - 1);
        const float* rowp = seq + (size_t)ltc * DH + quad * 16;
        float xy = 0.0f, y2 = 0.0f;
        #pragma unroll
        for (int j = 0; j < 4; ++j) {
            float4 yv = *reinterpret_cast<const float4*>(rowp + j * 4);
            xy = fmaf(xv[j].x, yv.x, xy); xy = fmaf(xv[j].y, yv.y, xy);
            xy = fmaf(xv[j].z, yv.z, xy); xy = fmaf(xv[j].w, yv.w, xy);
            y2 = fmaf(yv.x, yv.x, y2); y2 = fmaf(yv.y, yv.y, y2);
            y2 = fmaf(yv.z, yv.z, y2); y2 = fmaf(yv.w, yv.w, y2);
        }
        xy += __shfl_xor(xy, 1, 64); xy += __shfl_xor(xy, 2, 64);
        y2 += __shfl_xor(y2, 1, 64); y2 += __shfl_xor(y2, 2, 64);
        const float d2 = fmaf(-2.0f, xy, x2 + y2);
        d_pos = pdist(x2, y2, d2);
    }
    if (c == 0 && lane == 0) wpos[s] = d_pos;

    const float ma = MARGIN + d_pos;
    float hg = 0.0f;

    if (!empty) {
        #pragma unroll
        for (int it = 0; it < 4; ++it) {
            const int rowbase = c * RPC + it * 16;
            if (rowbase + 15 <= lt) continue;   // whole sub-iter masked out
            const int row = rowbase + rg;
            const float* rowp = seq + (size_t)row * DH + quad * 16;
            float xy = 0.0f, y2 = 0.0f;
            #pragma unroll
            for (int j = 0; j < 4; ++j) {
                float4 yv = *reinterpret_cast<const float4*>(rowp + j * 4);
                xy = fmaf(xv[j].x, yv.x, xy); xy = fmaf(xv[j].y, yv.y, xy);
                xy = fmaf(xv[j].z, yv.z, xy); xy = fmaf(xv[j].w, yv.w, xy);
                y2 = fmaf(yv.x, yv.x, y2); y2 = fmaf(yv.y, yv.y, y2);
                y2 = fmaf(yv.z, yv.z, y2); y2 = fmaf(yv.w, yv.w, y2);
            }
            xy += __shfl_xor(xy, 1, 64); xy += __shfl_xor(xy, 2, 64);
            y2 += __shfl_xor(y2, 1, 64); y2 += __shfl_xor(y2, 2, 64);
            const float d2 = fmaf(-2.0f, xy, x2 + y2);
            const float dneg = pdist(x2, y2, d2);
            const float h = fmaxf(ma - dneg, 0.0f);
            hg += (row > lt) ? h : 0.0f;
        }
        // sum across the 16 row-groups (uniform within each quad)
        hg += __shfl_xor(hg, 4, 64);
        hg += __shfl_xor(hg, 8, 64);
        hg += __shfl_xor(hg, 16, 64);
        hg += __shfl_xor(hg, 32, 64);
    }

    if (lane == 0) wneg[c * NSAMP + s] = hg;
}

__global__ __launch_bounds__(64) void reduce_kernel(
    const float* __restrict__ wneg,
    const float* __restrict__ wpos,
    const int*   __restrict__ align_idx,
    const int*   __restrict__ lookahead_p,
    float* __restrict__ out)
{
    const int lane = threadIdx.x;
    const int lk = lookahead_p[0];
    float pn = 0.0f, pv = 0.0f, nn = 0.0f, nc = 0.0f;
    #pragma unroll
    for (int k = 0; k < NSAMP / 64; ++k) {
        const int s = k * 64 + lane;
        float h = 0.0f;
        #pragma unroll
        for (int cc = 0; cc < CHUNKS; ++cc)
            h += wneg[cc * NSAMP + s];          // coalesced across lanes
        const int lt = align_idx[s * 2 + 1] + lk;
        const bool v = (lt >= 0) && (lt < Lc);
        const float cnt = v ? (float)(Lc - 1 - lt) : 0.0f;  // #rows > lt
        const float hneg = (cnt > 0.0f) ? 1.0f : 0.0f;
        nn += (h / fmaxf(cnt, 1.0f)) * hneg;
        nc += hneg;
        pn += wpos[s];
        pv += v ? 1.0f : 0.0f;
    }
    #pragma unroll
    for (int m = 1; m < 64; m <<= 1) {
        pn += __shfl_xor(pn, m, 64);
        pv += __shfl_xor(pv, m, 64);
        nn += __shfl_xor(nn, m, 64);
        nc += __shfl_xor(nc, m, 64);
    }
    if (lane == 0) {
        const float pos_term = pn / fmaxf(pv, 1.0f);
        const float neg_term = nn / fmaxf(nc, 1.0f);
        out[0] = pos_term + NEG_WEIGHT * neg_term;
    }
}

extern "C" void kernel_launch(void* const* d_in, const int* in_sizes, int n_in,
                              void* d_out, int out_size, void* d_ws, size_t ws_size,
                              hipStream_t stream) {
    const float* h_curr    = (const float*)d_in[0];
    const float* demo_h    = (const float*)d_in[1];
    const int*   align_idx = (const int*)d_in[2];
    const int*   lookahead = (const int*)d_in[3];
    float* out  = (float*)d_out;
    float* wneg = (float*)d_ws;                       // CHUNKS*NSAMP floats
    float* wpos = (float*)d_ws + CHUNKS * NSAMP;      // NSAMP floats

    sample_kernel<<<NSAMP * CHUNKS, 64, 0, stream>>>(
        h_curr, demo_h, align_idx, lookahead, wneg, wpos);
    reduce_kernel<<<1, 64, 0, stream>>>(wneg, wpos, align_idx, lookahead, out);
}

// Round 5
// 25.372 us; speedup vs baseline: 1.9341x; 1.9341x over previous
//
#include <hip/hip_runtime.h>
#include <math.h>

#define MARGIN 0.2f
#define NEG_WEIGHT 0.5f

constexpr int Bc = 64, Nc = 16, Lc = 1024, DH = 64, Ac = 8;
constexpr int NSAMP = Bc * Ac;            // 512
constexpr int CHUNKS = 16;                // chunks per sample
constexpr int ROWS_PER_CHUNK = Lc / CHUNKS;  // 64 rows, one wave each

__device__ __forceinline__ float fast_acosh(float z) {
    // z >= 1 + 1e-7 guaranteed by clamp
    return __logf(z + __builtin_sqrtf(z * z - 1.0f));
}

__device__ __forceinline__ float pdist(float x2, float y2, float d2) {
    x2 = fminf(x2, 0.999999f);
    y2 = fminf(y2, 0.999999f);
    float num = 2.0f * d2;
    float den = (1.0f - x2) * (1.0f - y2);
    float ratio = num * __builtin_amdgcn_rcpf(fmaxf(den, 1e-15f));
    float z = 1.0f + fmaxf(ratio, 1.0f + 1e-7f);
    return fast_acosh(z);
}

// one wave (64 threads) per block; block = (sample, chunk-of-64-rows)
// lane layout: quad = lane&3 owns dims [quad*16, quad*16+16); rg = lane>>2 owns a row
__global__ __launch_bounds__(64) void sample_kernel(
    const float* __restrict__ h_curr,
    const float* __restrict__ demo_h,
    const int*   __restrict__ align_idx,
    const int*   __restrict__ lookahead_p,
    float* __restrict__ ws)
{
    const int blk  = blockIdx.x;
    const int s    = blk >> 4;         // sample 0..511
    const int c    = blk & 15;         // chunk  0..15
    const int b    = s >> 3;           // s / Ac
    const int lane = threadIdx.x;
    const int quad = lane & 3;
    const int rg   = lane >> 2;        // 0..15

    const int n0 = align_idx[s * 2 + 0];
    const int l0 = align_idx[s * 2 + 1];
    const int lk = lookahead_p[0];
    const int lt = l0 + lk;
    const bool valid = (lt >= 0) && (lt < Lc);

    if (!valid) {
        if (lane == 0) {
            float* wneg = ws + (size_t)(s * CHUNKS + c) * 2;
            wneg[0] = 0.0f; wneg[1] = 0.0f;
            if (c == 0) {
                float* wpos = ws + (size_t)NSAMP * CHUNKS * 2 + (size_t)s * 2;
                wpos[0] = 0.0f; wpos[1] = 0.0f;
            }
        }
        return;
    }

    // >>> the ONE change vs R2: chunks whose rows are all <= lt contribute
    // nothing to the hinge sum — exit without reading the 16 KB chunk.
    // (c == 0 must stay alive to produce d_pos.)
    const bool dead = (c * ROWS_PER_CHUNK + (ROWS_PER_CHUNK - 1)) <= lt;
    if (dead && c != 0) {
        if (lane == 0) {
            float* wneg = ws + (size_t)(s * CHUNKS + c) * 2;
            wneg[0] = 0.0f; wneg[1] = 0.0f;
        }
        return;
    }
    // <<<

    const int lt_c = min(max(lt, 0), Lc - 1);

    const float* __restrict__ xrow = h_curr + (size_t)b * DH + quad * 16;
    const float* __restrict__ seq  = demo_h + (((size_t)b * Nc + (size_t)n0) * Lc) * DH;

    // x fragment: 16 dims per lane
    float4 xv[4];
    #pragma unroll
    for (int j = 0; j < 4; ++j)
        xv[j] = *reinterpret_cast<const float4*>(xrow + j * 4);

    float x2 = 0.0f;
    #pragma unroll
    for (int j = 0; j < 4; ++j) {
        x2 = fmaf(xv[j].x, xv[j].x, x2);
        x2 = fmaf(xv[j].y, xv[j].y, x2);
        x2 = fmaf(xv[j].z, xv[j].z, x2);
        x2 = fmaf(xv[j].w, xv[j].w, x2);
    }
    x2 += __shfl_xor(x2, 1, 64);
    x2 += __shfl_xor(x2, 2, 64);   // x2 valid in all lanes of each quad-group

    // d_pos from row lt_c (every row-group reads the same row -> identical result)
    float d_pos;
    {
        const float* rowp = seq + (size_t)lt_c * DH + quad * 16;
        float d2 = 0.0f, y2 = 0.0f;
        #pragma unroll
        for (int j = 0; j < 4; ++j) {
            float4 yv = *reinterpret_cast<const float4*>(rowp + j * 4);
            float dx = xv[j].x - yv.x, dy = xv[j].y - yv.y;
            float dz = xv[j].z - yv.z, dw = xv[j].w - yv.w;
            d2 = fmaf(dx, dx, d2); d2 = fmaf(dy, dy, d2);
            d2 = fmaf(dz, dz, d2); d2 = fmaf(dw, dw, d2);
            y2 = fmaf(yv.x, yv.x, y2); y2 = fmaf(yv.y, yv.y, y2);
            y2 = fmaf(yv.z, yv.z, y2); y2 = fmaf(yv.w, yv.w, y2);
        }
        d2 += __shfl_xor(d2, 1, 64); d2 += __shfl_xor(d2, 2, 64);
        y2 += __shfl_xor(y2, 1, 64); y2 += __shfl_xor(y2, 2, 64);
        d_pos = pdist(x2, y2, d2);
    }

    if (dead) {   // only possible for c == 0: write d_pos, zero hinge, exit
        if (lane == 0) {
            float* wneg = ws + (size_t)(s * CHUNKS + c) * 2;
            wneg[0] = 0.0f; wneg[1] = 0.0f;
            float* wpos = ws + (size_t)NSAMP * CHUNKS * 2 + (size_t)s * 2;
            wpos[0] = d_pos; wpos[1] = 1.0f;
        }
        return;
    }

    // negatives: 64 rows of this chunk, 16 rows per pass (one per row-group)
    float hinge_acc = 0.0f, cnt_acc = 0.0f;
    #pragma unroll
    for (int it = 0; it < 4; ++it) {
        const int row = c * ROWS_PER_CHUNK + it * 16 + rg;
        const float* rowp = seq + (size_t)row * DH + quad * 16;
        float d2 = 0.0f, y2 = 0.0f;
        #pragma unroll
        for (int j = 0; j < 4; ++j) {
            float4 yv = *reinterpret_cast<const float4*>(rowp + j * 4);
            float dx = xv[j].x - yv.x, dy = xv[j].y - yv.y;
            float dz = xv[j].z - yv.z, dw = xv[j].w - yv.w;
            d2 = fmaf(dx, dx, d2); d2 = fmaf(dy, dy, d2);
            d2 = fmaf(dz, dz, d2); d2 = fmaf(dw, dw, d2);
            y2 = fmaf(yv.x, yv.x, y2); y2 = fmaf(yv.y, yv.y, y2);
            y2 = fmaf(yv.z, yv.z, y2); y2 = fmaf(yv.w, yv.w, y2);
        }
        d2 += __shfl_xor(d2, 1, 64); d2 += __shfl_xor(d2, 2, 64);
        y2 += __shfl_xor(y2, 1, 64); y2 += __shfl_xor(y2, 2, 64);
        float dneg = pdist(x2, y2, d2);
        if (row > lt) {
            hinge_acc += fmaxf(MARGIN - dneg + d_pos, 0.0f);
            cnt_acc   += 1.0f;
        }
    }

    // values are uniform within each quad; sum across the 16 row-groups only
    #pragma unroll
    for (int m = 4; m < 64; m <<= 1) {
        hinge_acc += __shfl_xor(hinge_acc, m, 64);
        cnt_acc   += __shfl_xor(cnt_acc,   m, 64);
    }

    if (lane == 0) {
        float* wneg = ws + (size_t)(s * CHUNKS + c) * 2;
        wneg[0] = hinge_acc;
        wneg[1] = cnt_acc;
        if (c == 0) {
            float* wpos = ws + (size_t)NSAMP * CHUNKS * 2 + (size_t)s * 2;
            wpos[0] = d_pos; wpos[1] = 1.0f;
        }
    }
}

__global__ __launch_bounds__(256) void reduce_kernel(
    const float* __restrict__ ws, float* __restrict__ out)
{
    const int tid = threadIdx.x;
    float pn = 0.0f, pv = 0.0f, nn = 0.0f, nc = 0.0f;
    for (int s = tid; s < NSAMP; s += 256) {
        float h = 0.0f, ct = 0.0f;
        #pragma unroll
        for (int c = 0; c < CHUNKS; ++c) {
            h  += ws[(size_t)(s * CHUNKS + c) * 2 + 0];
            ct += ws[(size_t)(s * CHUNKS + c) * 2 + 1];
        }
        float per_sample = h / fmaxf(ct, 1.0f);
        float has_neg = (ct > 0.0f) ? 1.0f : 0.0f;
        nn += per_sample * has_neg;
        nc += has_neg;
        pn += ws[(size_t)NSAMP * CHUNKS * 2 + (size_t)s * 2 + 0];
        pv += ws[(size_t)NSAMP * CHUNKS * 2 + (size_t)s * 2 + 1];
    }
    __shared__ float4 sh[256];
    sh[tid] = make_float4(pn, pv, nn, nc);
    __syncthreads();
    for (int off = 128; off > 0; off >>= 1) {
        if (tid < off) {
            sh[tid].x += sh[tid + off].x;
            sh[tid].y += sh[tid + off].y;
            sh[tid].z += sh[tid + off].z;
            sh[tid].w += sh[tid + off].w;
        }
        __syncthreads();
    }
    if (tid == 0) {
        float pos_term = sh[0].x / fmaxf(sh[0].y, 1.0f);
        float neg_term = sh[0].z / fmaxf(sh[0].w, 1.0f);
        out[0] = pos_term + NEG_WEIGHT * neg_term;
    }
}

extern "C" void kernel_launch(void* const* d_in, const int* in_sizes, int n_in,
                              void* d_out, int out_size, void* d_ws, size_t ws_size,
                              hipStream_t stream) {
    const float* h_curr    = (const float*)d_in[0];
    const float* demo_h    = (const float*)d_in[1];
    const int*   align_idx = (const int*)d_in[2];
    const int*   lookahead = (const int*)d_in[3];
    float* out = (float*)d_out;
    float* ws  = (float*)d_ws;

    sample_kernel<<<NSAMP * CHUNKS, 64, 0, stream>>>(h_curr, demo_h, align_idx, lookahead, ws);
    reduce_kernel<<<1, 256, 0, stream>>>(ws, out);
}